// Round 1
// baseline (28.354 us; speedup 1.0000x reference)
//
#include <hip/hip_runtime.h>
#include <stdint.h>

#define D_E 64
#define D_R 32
#define IN_CH 96
#define NB 2

// ---------------------------------------------------------------------------
// Kernel 1: scan dst half of edge_index for dst == unseen_index, compact
// matching edge ids into a list in d_ws via atomic counter.
// ---------------------------------------------------------------------------
__global__ void scan_dst_kernel(const int* __restrict__ dst, int E,
                                const int* __restrict__ unseen_ptr,
                                int* __restrict__ cnt,
                                int* __restrict__ list, int capacity)
{
    const int unseen = *unseen_ptr;
    const int idx = blockIdx.x * blockDim.x + threadIdx.x;
    const int stride = gridDim.x * blockDim.x;

    // Vector path only if the dst pointer is 16B-aligned and E%4==0
    int E4 = 0;
    if (((uintptr_t)dst & 15u) == 0 && (E & 3) == 0) E4 = E >> 2;

    const int4* d4 = (const int4*)dst;
    for (int i = idx; i < E4; i += stride) {
        int4 v = d4[i];
        int base = i << 2;
        if (v.x == unseen) { int p = atomicAdd(cnt, 1); if (p < capacity) list[p] = base + 0; }
        if (v.y == unseen) { int p = atomicAdd(cnt, 1); if (p < capacity) list[p] = base + 1; }
        if (v.z == unseen) { int p = atomicAdd(cnt, 1); if (p < capacity) list[p] = base + 2; }
        if (v.w == unseen) { int p = atomicAdd(cnt, 1); if (p < capacity) list[p] = base + 3; }
    }
    // Scalar tail (covers everything when the vector path is disabled)
    for (int i = (E4 << 2) + idx; i < E; i += stride) {
        if (dst[i] == unseen) { int p = atomicAdd(cnt, 1); if (p < capacity) list[p] = i; }
    }
}

// ---------------------------------------------------------------------------
// Kernel 2: one block. Stage basis in LDS, each wave processes one matching
// edge (lane o = output channel), accumulate msg into LDS, finalize mean+ReLU.
// ---------------------------------------------------------------------------
__global__ void __launch_bounds__(256)
gather_compute_kernel(const float* __restrict__ ent,
                      const float* __restrict__ rel,
                      const float* __restrict__ att,
                      const float* __restrict__ basis,
                      const int* __restrict__ node_id,
                      const int* __restrict__ edge_index,   // src half at [0,E)
                      const int* __restrict__ etype,
                      const int* __restrict__ rindex,
                      const int* __restrict__ cnt_ptr,
                      const int* __restrict__ list, int capacity,
                      float* __restrict__ out)
{
    __shared__ float sb[NB * IN_CH * D_E];   // 48 KiB
    __shared__ float sacc[D_E];

    const int tid = threadIdx.x;

    for (int i = tid; i < NB * IN_CH * D_E; i += blockDim.x) sb[i] = basis[i];
    if (tid < D_E) sacc[tid] = 0.0f;
    __syncthreads();

    int n = *cnt_ptr;
    int nl = n < capacity ? n : capacity;

    const int wave = tid >> 6;
    const int o = tid & 63;
    const int nwaves = blockDim.x >> 6;

    for (int e = wave; e < nl; e += nwaves) {
        const int eid = list[e];
        const int s   = edge_index[eid];
        const int nid = node_id[s];
        const int et  = etype[eid];
        const int ri  = rindex[eid];
        const float c0 = att[et * 2 + 0];
        const float c1 = att[et * 2 + 1];
        const float* __restrict__ xr = ent + (long)nid * D_E;
        const float* __restrict__ rr = rel + (long)ri * D_R;

        float m = 0.0f;
        #pragma unroll 8
        for (int i = 0; i < D_E; ++i) {
            float xi = xr[i];
            m += xi * (c0 * sb[i * D_E + o] + c1 * sb[IN_CH * D_E + i * D_E + o]);
        }
        #pragma unroll 8
        for (int i = 0; i < D_R; ++i) {
            float xi = rr[i];
            int ii = D_E + i;
            m += xi * (c0 * sb[ii * D_E + o] + c1 * sb[IN_CH * D_E + ii * D_E + o]);
        }
        atomicAdd(&sacc[o], m);
    }
    __syncthreads();

    if (tid < D_E) {
        float denom = fmaxf((float)n, 1.0f);   // reference: count over ALL matching edges
        float v = sacc[tid] / denom;
        out[tid] = fmaxf(v, 0.0f);
    }
}

extern "C" void kernel_launch(void* const* d_in, const int* in_sizes, int n_in,
                              void* d_out, int out_size, void* d_ws, size_t ws_size,
                              hipStream_t stream)
{
    const float* ent    = (const float*)d_in[0];   // [N_ENT, 64]
    const float* rel    = (const float*)d_in[1];   // [R, 32]
    const float* att    = (const float*)d_in[2];   // [2R, 2]
    const float* basis  = (const float*)d_in[3];   // [2, 96, 64]
    const int* node_id  = (const int*)d_in[4];     // [N]
    const int* eindex   = (const int*)d_in[5];     // [2, E] flattened
    const int* etype    = (const int*)d_in[6];     // [E]
    const int* rindex   = (const int*)d_in[7];     // [E]
    const int* unseen   = (const int*)d_in[8];     // [1]

    const int E = in_sizes[6];
    const int* dst = eindex + E;                   // second row

    // ws layout: [0..3] counter (int), [16..] edge list (ints)
    int* cnt  = (int*)d_ws;
    int* list = (int*)((char*)d_ws + 16);
    int capacity = (int)((ws_size - 16) / sizeof(int));
    if (capacity > E) capacity = E;

    hipMemsetAsync(d_ws, 0, 16, stream);

    int threads = 256;
    int work = (E + 3) / 4;
    int blocks = (work + threads - 1) / threads;
    if (blocks > 1024) blocks = 1024;
    scan_dst_kernel<<<blocks, threads, 0, stream>>>(dst, E, unseen, cnt, list, capacity);

    gather_compute_kernel<<<1, 256, 0, stream>>>(ent, rel, att, basis, node_id,
                                                 eindex, etype, rindex,
                                                 cnt, list, capacity,
                                                 (float*)d_out);
}

// Round 2
// 16.203 us; speedup vs baseline: 1.7499x; 1.7499x over previous
//
#include <hip/hip_runtime.h>
#include <stdint.h>

#define D_E 64
#define D_R 32
#define IN_CH 96

// ws layout: byte 0: int cnt; byte 256: float acc[64]. Memset first 512B.

// ---------------------------------------------------------------------------
// Fused kernel: scan dst for matches; blocks that find matches process them
// in-place (wave-parallel over the 64 output channels) and atomically
// accumulate into acc[] in d_ws. ~20 of ~1M edges match, so almost all
// blocks exit right after the scan.
// ---------------------------------------------------------------------------
__global__ void __launch_bounds__(256)
scan_compute_kernel(const int* __restrict__ dst,     // edge_index row 1
                    const int* __restrict__ src,     // edge_index row 0
                    int E,
                    const int* __restrict__ unseen_ptr,
                    const int* __restrict__ node_id,
                    const int* __restrict__ etype,
                    const int* __restrict__ rindex,
                    const float* __restrict__ ent,
                    const float* __restrict__ rel,
                    const float* __restrict__ att,
                    const float* __restrict__ basis, // [2][96][64]
                    int* __restrict__ cnt,
                    float* __restrict__ acc)
{
    __shared__ int lcnt;
    __shared__ int llist[1024];          // worst case: every lane matches x4

    if (threadIdx.x == 0) lcnt = 0;
    __syncthreads();

    const int unseen = *unseen_ptr;
    const int tid = threadIdx.x;
    const int base = (blockIdx.x * blockDim.x + tid) << 2;

    const bool vec_ok = (((uintptr_t)dst & 15u) == 0);
    if (vec_ok && base + 3 < E) {
        int4 v = *(const int4*)(dst + base);
        if (v.x == unseen) { int p = atomicAdd(&lcnt, 1); llist[p] = base + 0; }
        if (v.y == unseen) { int p = atomicAdd(&lcnt, 1); llist[p] = base + 1; }
        if (v.z == unseen) { int p = atomicAdd(&lcnt, 1); llist[p] = base + 2; }
        if (v.w == unseen) { int p = atomicAdd(&lcnt, 1); llist[p] = base + 3; }
    } else {
        #pragma unroll
        for (int k = 0; k < 4; ++k) {
            int i = base + k;
            if (i < E && dst[i] == unseen) { int p = atomicAdd(&lcnt, 1); llist[p] = i; }
        }
    }
    __syncthreads();

    const int n = lcnt;
    if (n == 0) return;                  // fast path for ~99.98% of blocks
    if (tid == 0) atomicAdd(cnt, n);

    const int wave = tid >> 6;
    const int o = tid & 63;
    const int nw = blockDim.x >> 6;

    const float* __restrict__ B0 = basis;
    const float* __restrict__ B1 = basis + IN_CH * D_E;

    for (int e = wave; e < n; e += nw) {
        const int eid = llist[e];
        const int s   = src[eid];
        const int nid = node_id[s];
        const int et  = etype[eid];
        const int ri  = rindex[eid];
        const float c0 = att[et * 2 + 0];
        const float c1 = att[et * 2 + 1];

        // Coalesced row loads: lane i holds x[i] (ent row) / r[i] (rel row).
        const float xv = ent[(long)nid * D_E + o];
        const float rv = (o < D_R) ? rel[(long)ri * D_R + o] : 0.0f;

        float m = 0.0f;
        #pragma unroll 16
        for (int i = 0; i < D_E; ++i) {
            const float xi = __shfl(xv, i);
            m = fmaf(xi * c0, B0[i * D_E + o], m);
            m = fmaf(xi * c1, B1[i * D_E + o], m);
        }
        #pragma unroll 16
        for (int i = 0; i < D_R; ++i) {
            const float xi = __shfl(rv, i);
            const int ii = D_E + i;
            m = fmaf(xi * c0, B0[ii * D_E + o], m);
            m = fmaf(xi * c1, B1[ii * D_E + o], m);
        }
        atomicAdd(&acc[o], m);
    }
}

// ---------------------------------------------------------------------------
// Finalize: one wave. mean + ReLU.
// ---------------------------------------------------------------------------
__global__ void finalize_kernel(const int* __restrict__ cnt,
                                const float* __restrict__ acc,
                                float* __restrict__ out)
{
    const int o = threadIdx.x;
    if (o < D_E) {
        const float denom = fmaxf((float)(*cnt), 1.0f);
        out[o] = fmaxf(acc[o] / denom, 0.0f);
    }
}

extern "C" void kernel_launch(void* const* d_in, const int* in_sizes, int n_in,
                              void* d_out, int out_size, void* d_ws, size_t ws_size,
                              hipStream_t stream)
{
    const float* ent    = (const float*)d_in[0];   // [N_ENT, 64]
    const float* rel    = (const float*)d_in[1];   // [R, 32]
    const float* att    = (const float*)d_in[2];   // [2R, 2]
    const float* basis  = (const float*)d_in[3];   // [2, 96, 64]
    const int* node_id  = (const int*)d_in[4];     // [N]
    const int* eindex   = (const int*)d_in[5];     // [2, E]
    const int* etype    = (const int*)d_in[6];     // [E]
    const int* rindex   = (const int*)d_in[7];     // [E]
    const int* unseen   = (const int*)d_in[8];     // [1]

    const int E = in_sizes[6];
    const int* src = eindex;
    const int* dst = eindex + E;

    int*   cnt = (int*)d_ws;
    float* acc = (float*)((char*)d_ws + 256);

    hipMemsetAsync(d_ws, 0, 512, stream);

    const int threads = 256;
    const int per_block = threads * 4;
    const int blocks = (E + per_block - 1) / per_block;

    scan_compute_kernel<<<blocks, threads, 0, stream>>>(
        dst, src, E, unseen, node_id, etype, rindex,
        ent, rel, att, basis, cnt, acc);

    finalize_kernel<<<1, 64, 0, stream>>>(cnt, acc, (float*)d_out);
}